// Round 4
// baseline (233.003 us; speedup 1.0000x reference)
//
#include <hip/hip_runtime.h>

// Correlation: out[b,(p+4)*9+(q+4),y,x] = (1/128) * sum_c A[b,c,y,x]*B[b,c,y+p,x+q]
// A,B = (8,128,128,128) fp32; out = (8,81,128,128) fp32. B zero-padded.
//
// R4: R3 with compile fix (h2 = __fp16 ext_vector(2), matching cvt_pkrtz/fdot2).
// f16 channel-pair packing, v_dot2_f32_f16 (2 MACs/instr, fp32 accumulate),
// LDS double-buffer -> ONE barrier per chunk, register prefetch one chunk ahead.

typedef __fp16 h2 __attribute__((ext_vector_type(2)));

#define BW2 144   // padded B row in half2 units; j = x+4, valid j in [0,136), pad to 144

#if __has_builtin(__builtin_amdgcn_fdot2)
  #define FDOT2(a, b, c) __builtin_amdgcn_fdot2((a), (b), (c), false)
#else
  static __device__ inline float FDOT2(h2 a, h2 b, float c) {
      return c + (float)a.x * (float)b.x + (float)a.y * (float)b.y;
  }
#endif

static __device__ inline float pk2f(float lo, float hi) {
    h2 v = __builtin_amdgcn_cvt_pkrtz(lo, hi);   // (f16(lo), f16(hi)) packed
    return __builtin_bit_cast(float, v);
}
static __device__ inline h2 f2h2(float f) { return __builtin_bit_cast(h2, f); }

__global__ __launch_bounds__(576, 5)
void corr_kernel(const float* __restrict__ A, const float* __restrict__ B,
                 float* __restrict__ out)
{
    const int bidx = blockIdx.x;
    const int bb = bidx & 7;          // batch -> XCD affinity
    const int y  = bidx >> 3;

    const int tid  = threadIdx.x;
    const int wave = tid >> 6;        // 0..8 -> p = wave-4
    const int lane = tid & 63;
    const int cs   = lane >> 5;       // pair-select within chunk
    const int x0   = (lane & 31) << 2;

    __shared__ h2 a_s[2][2][128];     // [buf][pair][x]
    __shared__ h2 b_s[2][9][2][BW2];  // [buf][p][pair][j]

    // one-time zero of b_s (pads j<4 / j>=132 and OOB rows stay zero forever)
    {
        float4* p = (float4*)&b_s[0][0][0][0];
        const int total = 2 * 9 * 2 * BW2 / 4;   // 1296 float4
        for (int i = tid; i < total; i += 576) p[i] = make_float4(0.f, 0.f, 0.f, 0.f);
    }

    float acc[9][4];
    #pragma unroll
    for (int q = 0; q < 9; ++q)
        #pragma unroll
        for (int i = 0; i < 4; ++i) acc[q][i] = 0.f;

    const long plane = 128L * 128L;
    const float* Abase = A + (long)bb * 128 * plane + (long)y * 128;
    const float* Bbase = B + (long)bb * 128 * plane;

    // B staging map: 18 rows (9 p x 2 pairs) x 32 threads
    const int br  = tid >> 5;            // 0..17
    const int bi4 = (tid & 31) << 2;     // float4 column
    const int bpr = br >> 1;             // p row 0..8
    const int bpp = br & 1;              // pair 0/1
    const int bys = y + bpr - 4;
    const bool bval = ((unsigned)bys < 128u) && (br < 18);
    const float* Bsrc = Bbase + (long)bys * 128 + bi4;   // + c*plane per chunk

    // A staging map: threads < 64: 2 pairs x 32 columns
    const bool aact = tid < 64;
    const int app = (tid >> 5) & 1;
    const int ai4 = (tid & 31) << 2;

    float4 rb0 = make_float4(0.f,0.f,0.f,0.f), rb1 = rb0, ra0 = rb0, ra1 = rb0;

    auto load_chunk = [&](int ch0) {
        if (bval) {
            const int c0 = ch0 + (bpp << 1);
            rb0 = *(const float4*)(Bsrc + (long)c0 * plane);
            rb1 = *(const float4*)(Bsrc + (long)(c0 + 1) * plane);
        }
        if (aact) {
            const int c0 = ch0 + (app << 1);
            ra0 = *(const float4*)(Abase + (long)c0 * plane + ai4);
            ra1 = *(const float4*)(Abase + (long)(c0 + 1) * plane + ai4);
        }
    };
    auto write_stage = [&](int buf) {
        if (bval) {
            float4 w;
            w.x = pk2f(rb0.x, rb1.x);
            w.y = pk2f(rb0.y, rb1.y);
            w.z = pk2f(rb0.z, rb1.z);
            w.w = pk2f(rb0.w, rb1.w);
            *(float4*)&b_s[buf][bpr][bpp][4 + bi4] = w;   // j = 4 + x
        }
        if (aact) {
            float4 w;
            w.x = pk2f(ra0.x, ra1.x);
            w.y = pk2f(ra0.y, ra1.y);
            w.z = pk2f(ra0.z, ra1.z);
            w.w = pk2f(ra0.w, ra1.w);
            *(float4*)&a_s[buf][app][ai4] = w;
        }
    };

    // prologue: chunk0 -> buf0, start chunk1 loads
    load_chunk(0);
    __syncthreads();          // zero-init visible before first stage writes
    write_stage(0);
    load_chunk(4);
    __syncthreads();          // buf0 ready

    for (int k = 0; k < 32; ++k) {
        const int buf = k & 1;
        if (k + 1 < 32) write_stage(buf ^ 1);     // regs hold chunk k+1
        if (k + 2 < 32) load_chunk((k + 2) << 2); // overlap with compute
        // compute chunk k from buf: this lane's pair = cs
        {
            const float4 av = *(const float4*)&a_s[buf][cs][x0];
            const float4 b0 = *(const float4*)&b_s[buf][wave][cs][x0];
            const float4 b1 = *(const float4*)&b_s[buf][wave][cs][x0 + 4];
            const float4 b2 = *(const float4*)&b_s[buf][wave][cs][x0 + 8];
            const h2 a2[4] = { f2h2(av.x), f2h2(av.y), f2h2(av.z), f2h2(av.w) };
            const h2 w[12] = { f2h2(b0.x), f2h2(b0.y), f2h2(b0.z), f2h2(b0.w),
                               f2h2(b1.x), f2h2(b1.y), f2h2(b1.z), f2h2(b1.w),
                               f2h2(b2.x), f2h2(b2.y), f2h2(b2.z), f2h2(b2.w) };
            #pragma unroll
            for (int q = 0; q < 9; ++q)
                #pragma unroll
                for (int i = 0; i < 4; ++i)
                    acc[q][i] = FDOT2(a2[i], w[q + i], acc[q][i]);
        }
        __syncthreads();
    }

    // combine pair-split halves (lane L += lane L+32)
    #pragma unroll
    for (int q = 0; q < 9; ++q)
        #pragma unroll
        for (int i = 0; i < 4; ++i)
            acc[q][i] += __shfl_down(acc[q][i], 32);

    if (cs == 0) {
        const float scale = 1.0f / 128.0f;
        float* obase = out + (((long)bb * 81 + (long)wave * 9) * 128 + y) * 128 + x0;
        #pragma unroll
        for (int q = 0; q < 9; ++q) {
            const float4 v = make_float4(acc[q][0] * scale, acc[q][1] * scale,
                                         acc[q][2] * scale, acc[q][3] * scale);
            *(float4*)(obase + (long)q * plane) = v;
        }
    }
}

extern "C" void kernel_launch(void* const* d_in, const int* in_sizes, int n_in,
                              void* d_out, int out_size, void* d_ws, size_t ws_size,
                              hipStream_t stream) {
    const float* a = (const float*)d_in[0];
    const float* b = (const float*)d_in[1];
    float* out = (float*)d_out;
    hipLaunchKernelGGL(corr_kernel, dim3(1024), dim3(576), 0, stream, a, b, out);
}

// Round 5
// 197.497 us; speedup vs baseline: 1.1798x; 1.1798x over previous
//
#include <hip/hip_runtime.h>

// Correlation: out[b,(p+4)*9+(q+4),y,x] = (1/128) * sum_c A[b,c,y,x]*B[b,c,y+p,x+q]
// A,B = (8,128,128,128) fp32; out = (8,81,128,128) fp32. B zero-padded.
//
// R5: latency fix via small blocks. Block = 192 threads (3 waves) = one (b, y,
// p-group-of-3); grid 3072 -> ~10 blocks/CU resident, cross-block overlap hides
// global-load latency. Keeps R4's f16 pair-packing + v_dot2_f32_f16 + LDS
// double-buffer (1 barrier/chunk) + 1-chunk-ahead register prefetch.
// LDS = 10.75 KB/block.

typedef __fp16 h2 __attribute__((ext_vector_type(2)));

#define BW2 144   // padded B row in h2 units; j = x+4, valid j in [0,136), pad to 144

#if __has_builtin(__builtin_amdgcn_fdot2)
  #define FDOT2(a, b, c) __builtin_amdgcn_fdot2((a), (b), (c), false)
#else
  static __device__ inline float FDOT2(h2 a, h2 b, float c) {
      return c + (float)a.x * (float)b.x + (float)a.y * (float)b.y;
  }
#endif

static __device__ inline float pk2f(float lo, float hi) {
    h2 v = __builtin_amdgcn_cvt_pkrtz(lo, hi);   // (f16(lo), f16(hi)) packed
    return __builtin_bit_cast(float, v);
}
static __device__ inline h2 f2h2(float f) { return __builtin_bit_cast(h2, f); }

__global__ __launch_bounds__(192, 4)
void corr_kernel(const float* __restrict__ A, const float* __restrict__ B,
                 float* __restrict__ out)
{
    const int bidx = blockIdx.x;
    const int bb = bidx & 7;          // batch -> XCD affinity
    const int t2 = bidx >> 3;
    const int y  = t2 & 127;
    const int pg = t2 >> 7;           // p-group 0..2

    const int tid  = threadIdx.x;     // 0..191
    const int wave = tid >> 6;        // 0..2
    const int lane = tid & 63;
    const int cs   = lane >> 5;       // pair-select within 4-channel chunk
    const int x0   = (lane & 31) << 2;
    const int pr   = pg * 3 + wave;   // 0..8 -> p = pr-4

    __shared__ h2 a_s[2][2][128];     // [buf][pair][x]
    __shared__ h2 b_s[2][3][2][BW2];  // [buf][row-slot][pair][j]

    // one-time zero: pads (j<4, j>=132) and OOB rows stay zero forever
    {
        float4* p = (float4*)&a_s[0][0][0];   // a_s and b_s are adjacent? not guaranteed;
        // zero each array separately to be safe
        const int na = 2 * 2 * 128 / 4;       // 128 float4
        for (int i = tid; i < na; i += 192) p[i] = make_float4(0.f, 0.f, 0.f, 0.f);
        float4* pb = (float4*)&b_s[0][0][0][0];
        const int nb = 2 * 3 * 2 * BW2 / 4;   // 432 float4
        for (int i = tid; i < nb; i += 192) pb[i] = make_float4(0.f, 0.f, 0.f, 0.f);
    }

    float acc[9][4];
    #pragma unroll
    for (int q = 0; q < 9; ++q)
        #pragma unroll
        for (int i = 0; i < 4; ++i) acc[q][i] = 0.f;

    const long plane = 128L * 128L;
    const float* Abase = A + (long)bb * 128 * plane + (long)y * 128;
    const float* Bbase = B + (long)bb * 128 * plane;

    // B staging map: 6 row-pairs (3 row-slots x 2 pairs) x 32 threads, 1 packed f4/thread
    const int i4  = (tid & 31) << 2;     // float column
    const int rp  = tid >> 5;            // 0..5
    const int brw = rp >> 1;             // row slot 0..2
    const int bpp = rp & 1;              // pair 0/1
    const int bys = y + pg * 3 + brw - 4;
    const bool bval = (unsigned)bys < 128u;
    const float* Bsrc = Bbase + (long)bys * 128 + i4;   // + c*plane per chunk

    // A staging map: threads < 64: 2 pairs x 32 columns
    const bool aact = tid < 64;
    const int app = (tid >> 5) & 1;

    float4 rb0 = make_float4(0.f,0.f,0.f,0.f), rb1 = rb0, ra0 = rb0, ra1 = rb0;

    auto load_chunk = [&](int ch0) {
        if (bval) {
            const int c0 = ch0 + (bpp << 1);
            rb0 = *(const float4*)(Bsrc + (long)c0 * plane);
            rb1 = *(const float4*)(Bsrc + (long)(c0 + 1) * plane);
        }
        if (aact) {
            const int c0 = ch0 + (app << 1);
            ra0 = *(const float4*)(Abase + (long)c0 * plane + i4);
            ra1 = *(const float4*)(Abase + (long)(c0 + 1) * plane + i4);
        }
    };
    auto write_stage = [&](int buf) {
        if (bval) {
            float4 w;
            w.x = pk2f(rb0.x, rb1.x);
            w.y = pk2f(rb0.y, rb1.y);
            w.z = pk2f(rb0.z, rb1.z);
            w.w = pk2f(rb0.w, rb1.w);
            *(float4*)&b_s[buf][brw][bpp][4 + i4] = w;   // j = 4 + x
        }
        if (aact) {
            float4 w;
            w.x = pk2f(ra0.x, ra1.x);
            w.y = pk2f(ra0.y, ra1.y);
            w.z = pk2f(ra0.z, ra1.z);
            w.w = pk2f(ra0.w, ra1.w);
            *(float4*)&a_s[buf][app][i4] = w;
        }
    };

    // prologue: chunk0 -> buf0, start chunk1 loads
    load_chunk(0);
    __syncthreads();          // zero-init visible before first stage writes
    write_stage(0);
    load_chunk(4);
    __syncthreads();          // buf0 ready

    for (int k = 0; k < 32; ++k) {
        const int buf = k & 1;
        if (k + 1 < 32) write_stage(buf ^ 1);     // regs hold chunk k+1
        if (k + 2 < 32) load_chunk((k + 2) << 2); // overlap with compute
        // compute chunk k from buf: this lane's pair = cs, this wave's row slot = wave
        {
            const float4 av = *(const float4*)&a_s[buf][cs][x0];
            const float4 b0 = *(const float4*)&b_s[buf][wave][cs][x0];
            const float4 b1 = *(const float4*)&b_s[buf][wave][cs][x0 + 4];
            const float4 b2 = *(const float4*)&b_s[buf][wave][cs][x0 + 8];
            const h2 a2[4] = { f2h2(av.x), f2h2(av.y), f2h2(av.z), f2h2(av.w) };
            const h2 w[12] = { f2h2(b0.x), f2h2(b0.y), f2h2(b0.z), f2h2(b0.w),
                               f2h2(b1.x), f2h2(b1.y), f2h2(b1.z), f2h2(b1.w),
                               f2h2(b2.x), f2h2(b2.y), f2h2(b2.z), f2h2(b2.w) };
            #pragma unroll
            for (int q = 0; q < 9; ++q)
                #pragma unroll
                for (int i = 0; i < 4; ++i)
                    acc[q][i] = FDOT2(a2[i], w[q + i], acc[q][i]);
        }
        __syncthreads();
    }

    // combine pair-split halves (lane L += lane L+32)
    #pragma unroll
    for (int q = 0; q < 9; ++q)
        #pragma unroll
        for (int i = 0; i < 4; ++i)
            acc[q][i] += __shfl_down(acc[q][i], 32);

    if (cs == 0) {
        const float scale = 1.0f / 128.0f;
        float* obase = out + (((long)bb * 81 + (long)pr * 9) * 128 + y) * 128 + x0;
        #pragma unroll
        for (int q = 0; q < 9; ++q) {
            const float4 v = make_float4(acc[q][0] * scale, acc[q][1] * scale,
                                         acc[q][2] * scale, acc[q][3] * scale);
            *(float4*)(obase + (long)q * plane) = v;
        }
    }
}

extern "C" void kernel_launch(void* const* d_in, const int* in_sizes, int n_in,
                              void* d_out, int out_size, void* d_ws, size_t ws_size,
                              hipStream_t stream) {
    const float* a = (const float*)d_in[0];
    const float* b = (const float*)d_in[1];
    float* out = (float*)d_out;
    // grid: 8 batches * 128 y * 3 p-groups = 3072 blocks; 192 threads (3 waves)
    hipLaunchKernelGGL(corr_kernel, dim3(3072), dim3(192), 0, stream, a, b, out);
}